// Round 1
// baseline (323.853 us; speedup 1.0000x reference)
//
#include <hip/hip_runtime.h>

#define DIM 512
#define NTOK 2304
#define HEADS 8
#define HD 64
#define SCALE 0.125f
#define LN_EPS 1e-5f
#define BNC 2359296   // B*N*C = 2*2304*512

typedef __attribute__((ext_vector_type(8))) short short8;
typedef __attribute__((ext_vector_type(4))) float f32x4;

__device__ __forceinline__ short f2bf(float f) {
    union { float f; unsigned u; } x; x.f = f;
    unsigned r = (x.u + 0x7fffu + ((x.u >> 16) & 1u)) >> 16;
    return (short)(r & 0xffffu);
}

// ---------------- LN stats: mu, rsigma per (stream, b, n) ----------------
__global__ void k_stats(const float* __restrict__ x, const float* __restrict__ y,
                        float* __restrict__ mu, float* __restrict__ rs) {
    int id = blockIdx.x * 256 + threadIdx.x;   // [s][b][n], 9216 total
    int n = id % NTOK;
    int sb = id / NTOK;                        // s*2+b
    int s = sb >> 1, b = sb & 1;
    const float* src = (s ? y : x) + (size_t)b * DIM * NTOK + n;
    float sum = 0.f, sq = 0.f;
    for (int c = 0; c < DIM; c++) {
        float v = src[(size_t)c * NTOK];
        sum += v; sq += v * v;
    }
    float m = sum * (1.0f / DIM);
    float var = sq * (1.0f / DIM) - m * m;
    mu[id] = m;
    rs[id] = rsqrtf(var + LN_EPS);
}

// ---------------- normalize + transpose -> T[s][b][n][c] bf16 ----------------
__global__ void k_normT(const float* __restrict__ x, const float* __restrict__ y,
                        const float* __restrict__ mu, const float* __restrict__ rs,
                        const float* __restrict__ gx, const float* __restrict__ bx,
                        const float* __restrict__ gy, const float* __restrict__ by,
                        short* __restrict__ T) {
    __shared__ __align__(16) float tile[64][65];
    int nt = blockIdx.x, ct = blockIdx.y, sb = blockIdx.z;
    int s = sb >> 1, b = sb & 1;
    int n0 = nt * 64, c0 = ct * 64;
    const float* src = (s ? y : x) + (size_t)b * DIM * NTOK;
    int tid = threadIdx.x;
    for (int slot = tid; slot < 1024; slot += 256) {
        int r = slot >> 4, q = slot & 15;
        const float* p = src + (size_t)(c0 + r) * NTOK + n0 + q * 4;
        float4 v = *(const float4*)p;
        tile[r][q*4+0] = v.x; tile[r][q*4+1] = v.y;
        tile[r][q*4+2] = v.z; tile[r][q*4+3] = v.w;
    }
    __syncthreads();
    const float* g  = s ? gy : gx;
    const float* be = s ? by : bx;
    int nr = tid >> 2, cg = tid & 3;
    int n = n0 + nr;
    float m = mu[sb * NTOK + n], r_ = rs[sb * NTOK + n];
    short8 o0, o1;
    for (int i = 0; i < 8; i++) {
        int c = c0 + cg * 16 + i;
        o0[i] = f2bf((tile[cg*16+i][nr] - m) * r_ * g[c] + be[c]);
    }
    for (int i = 0; i < 8; i++) {
        int c = c0 + cg * 16 + 8 + i;
        o1[i] = f2bf((tile[cg*16+8+i][nr] - m) * r_ * g[c] + be[c]);
    }
    short* dst = T + ((size_t)sb * NTOK + n) * DIM + c0 + cg * 16;
    *(short8*)dst = o0;
    *(short8*)(dst + 8) = o1;
}

// ------------- weight transpose: Wt[j][c] = W[c][j] bf16, + combined bias -------------
__global__ void k_wtrans(const float* __restrict__ qv_w, const float* __restrict__ k_w,
                         const float* __restrict__ qv_b, const float* __restrict__ k_b,
                         short* __restrict__ Wt, float* __restrict__ bias) {
    __shared__ __align__(16) float tile[64][65];
    int jt = blockIdx.x, ct = blockIdx.y;    // jt 0..23 (cols j), ct 0..7 (rows c)
    int j0 = jt * 64, c0 = ct * 64;
    int tid = threadIdx.x;
    if (ct == 0 && tid < 64) {
        int j = j0 + tid;
        bias[j] = (j < 1024) ? qv_b[j] : k_b[j - 1024];
    }
    for (int slot = tid; slot < 1024; slot += 256) {
        int r = slot >> 4, q = slot & 15;
        int c = c0 + r;
        float4 v;
        if (j0 < 1024) v = *(const float4*)(qv_w + (size_t)c * 1024 + j0 + q * 4);
        else           v = *(const float4*)(k_w  + (size_t)c * 512  + (j0 - 1024) + q * 4);
        tile[r][q*4+0] = v.x; tile[r][q*4+1] = v.y;
        tile[r][q*4+2] = v.z; tile[r][q*4+3] = v.w;
    }
    __syncthreads();
    int jr = tid >> 2, cg = tid & 3;
    short8 o0, o1;
    for (int i = 0; i < 8; i++) o0[i] = f2bf(tile[cg*16+i][jr]);
    for (int i = 0; i < 8; i++) o1[i] = f2bf(tile[cg*16+8+i][jr]);
    short* dst = Wt + (size_t)(j0 + jr) * DIM + c0 + cg * 16;
    *(short8*)dst = o0;
    *(short8*)(dst + 8) = o1;
}

// ---------------- GEMM: QVK[sb][n][j] = T[sb] @ W + bias (bf16 MFMA) ----------------
__global__ void __launch_bounds__(256)
k_gemm(const short* __restrict__ T, const short* __restrict__ Wt,
       const float* __restrict__ bias, short* __restrict__ QVK) {
    __shared__ __align__(16) short As[64 * 72];
    __shared__ __align__(16) short Bs[64 * 72];
    int n0 = blockIdx.x * 64, j0 = blockIdx.y * 64, sb = blockIdx.z;
    int tid = threadIdx.x;
    int w = tid >> 6, l = tid & 63;
    int wr = w >> 1, wc = w & 1;
    int lrow = l & 15, lk = (l >> 4) * 8;
    const short* Abase = T + (size_t)sb * NTOK * DIM;
    f32x4 acc[2][2] = {};
    for (int kk = 0; kk < 8; kk++) {
        if (kk) __syncthreads();
        for (int slot = tid; slot < 512; slot += 256) {
            int r = slot >> 3, seg = slot & 7;
            *(short8*)&As[r * 72 + seg * 8] =
                *(const short8*)(Abase + (size_t)(n0 + r) * DIM + kk * 64 + seg * 8);
            *(short8*)&Bs[r * 72 + seg * 8] =
                *(const short8*)(Wt + (size_t)(j0 + r) * DIM + kk * 64 + seg * 8);
        }
        __syncthreads();
        for (int c = 0; c < 2; c++) {
            short8 a0 = *(const short8*)&As[(wr*32      + lrow) * 72 + c*32 + lk];
            short8 a1 = *(const short8*)&As[(wr*32 + 16 + lrow) * 72 + c*32 + lk];
            short8 b0 = *(const short8*)&Bs[(wc*32      + lrow) * 72 + c*32 + lk];
            short8 b1 = *(const short8*)&Bs[(wc*32 + 16 + lrow) * 72 + c*32 + lk];
            acc[0][0] = __builtin_amdgcn_mfma_f32_16x16x32_bf16(a0, b0, acc[0][0], 0, 0, 0);
            acc[0][1] = __builtin_amdgcn_mfma_f32_16x16x32_bf16(a0, b1, acc[0][1], 0, 0, 0);
            acc[1][0] = __builtin_amdgcn_mfma_f32_16x16x32_bf16(a1, b0, acc[1][0], 0, 0, 0);
            acc[1][1] = __builtin_amdgcn_mfma_f32_16x16x32_bf16(a1, b1, acc[1][1], 0, 0, 0);
        }
    }
    int rowq = (l >> 4) * 4;
    for (int i = 0; i < 2; i++)
        for (int j = 0; j < 2; j++) {
            int jj = j0 + wc * 32 + j * 16 + lrow;
            float bv = bias[jj];
            for (int reg = 0; reg < 4; reg++) {
                int n = n0 + wr * 32 + i * 16 + rowq + reg;
                QVK[((size_t)sb * NTOK + n) * 1536 + jj] = f2bf(acc[i][j][reg] + bv);
            }
        }
}

// ---------------- V transpose: VT[sb][j][n] from QVK v-region ----------------
__global__ void k_vtrans(const short* __restrict__ QVK, short* __restrict__ VT) {
    __shared__ short tile[64][65];
    int n0 = blockIdx.x * 64, j0 = blockIdx.y * 64, sb = blockIdx.z;   // j within [0,512)
    int tid = threadIdx.x;
    for (int slot = tid; slot < 512; slot += 256) {
        int r = slot >> 3, seg = slot & 7;
        short8 v = *(const short8*)(QVK + ((size_t)sb * NTOK + n0 + r) * 1536 + 512 + j0 + seg * 8);
        for (int i = 0; i < 8; i++) tile[r][seg * 8 + i] = v[i];
    }
    __syncthreads();
    int jr = tid >> 2, ng = tid & 3;
    short8 o0, o1;
    for (int i = 0; i < 8; i++) o0[i] = tile[ng*16+i][jr];
    for (int i = 0; i < 8; i++) o1[i] = tile[ng*16+8+i][jr];
    short* dst = VT + ((size_t)sb * 512 + j0 + jr) * NTOK + n0 + ng * 16;
    *(short8*)dst = o0;
    *(short8*)(dst + 8) = o1;
}

// ---------------- flash attention, both branches ----------------
__global__ void __launch_bounds__(256)
k_attn(const short* __restrict__ QVK, const short* __restrict__ VT,
       float* __restrict__ out) {
    __shared__ __align__(16) short Qs[64 * 72];
    __shared__ __align__(16) short Ks[64 * 72];
    __shared__ __align__(16) short Vt[64 * 72];
    __shared__ __align__(16) short Ps[4][16 * 72];
    int qt = blockIdx.x;              // 0..35
    int yb = blockIdx.y;              // 0..31
    int br = yb >> 4;
    int b  = (yb >> 3) & 1;
    int h  = yb & 7;
    int tid = threadIdx.x;
    int w = tid >> 6, l = tid & 63;
    int lrow = l & 15, lk = (l >> 4) * 8;
    int n0 = qt * 64;
    int qs = br, ks = 1 - br, vs = br;  // branch 0: Q=x,K=y,V=x; branch 1: Q=y,K=x,V=y
    const short* Qg = QVK + ((size_t)(qs * 2 + b) * NTOK) * 1536 + h * 64;
    const short* Kg = QVK + ((size_t)(ks * 2 + b) * NTOK) * 1536 + 1024 + h * 64;
    const short* Vg = VT + ((size_t)(vs * 2 + b) * 512 + h * 64) * NTOK;

    for (int slot = tid; slot < 512; slot += 256) {
        int r = slot >> 3, seg = slot & 7;
        *(short8*)&Qs[r * 72 + seg * 8] =
            *(const short8*)(Qg + (size_t)(n0 + r) * 1536 + seg * 8);
    }
    __syncthreads();
    short8 aq0 = *(const short8*)&Qs[(w * 16 + lrow) * 72 + lk];
    short8 aq1 = *(const short8*)&Qs[(w * 16 + lrow) * 72 + 32 + lk];

    f32x4 Oacc[4] = {};
    float m_i[4], l_i[4];
    for (int r = 0; r < 4; r++) { m_i[r] = -__builtin_inff(); l_i[r] = 0.f; }

    for (int mt = 0; mt < 36; mt++) {
        int m0 = mt * 64;
        __syncthreads();
        for (int slot = tid; slot < 512; slot += 256) {
            int r = slot >> 3, seg = slot & 7;
            *(short8*)&Ks[r * 72 + seg * 8] =
                *(const short8*)(Kg + (size_t)(m0 + r) * 1536 + seg * 8);
            *(short8*)&Vt[r * 72 + seg * 8] =
                *(const short8*)(Vg + (size_t)r * NTOK + m0 + seg * 8);
        }
        __syncthreads();

        f32x4 s[4];
        for (int sub = 0; sub < 4; sub++) {
            f32x4 a = {};
            short8 bk0 = *(const short8*)&Ks[(sub * 16 + lrow) * 72 + lk];
            short8 bk1 = *(const short8*)&Ks[(sub * 16 + lrow) * 72 + 32 + lk];
            a = __builtin_amdgcn_mfma_f32_16x16x32_bf16(aq0, bk0, a, 0, 0, 0);
            a = __builtin_amdgcn_mfma_f32_16x16x32_bf16(aq1, bk1, a, 0, 0, 0);
            s[sub] = a;
        }
        for (int sub = 0; sub < 4; sub++)
            for (int r = 0; r < 4; r++) s[sub][r] *= SCALE;

        float rowmax[4];
        for (int r = 0; r < 4; r++)
            rowmax[r] = fmaxf(fmaxf(s[0][r], s[1][r]), fmaxf(s[2][r], s[3][r]));
        for (int off = 1; off < 16; off <<= 1)
            for (int r = 0; r < 4; r++)
                rowmax[r] = fmaxf(rowmax[r], __shfl_xor(rowmax[r], off, 64));

        float alpha[4], nm[4];
        for (int r = 0; r < 4; r++) {
            nm[r] = fmaxf(m_i[r], rowmax[r]);
            alpha[r] = __expf(m_i[r] - nm[r]);
            m_i[r] = nm[r];
        }
        float rowsum[4] = {0.f, 0.f, 0.f, 0.f};
        for (int sub = 0; sub < 4; sub++)
            for (int r = 0; r < 4; r++) {
                float p = __expf(s[sub][r] - nm[r]);
                s[sub][r] = p;
                rowsum[r] += p;
            }
        for (int off = 1; off < 16; off <<= 1)
            for (int r = 0; r < 4; r++)
                rowsum[r] += __shfl_xor(rowsum[r], off, 64);
        for (int r = 0; r < 4; r++) l_i[r] = l_i[r] * alpha[r] + rowsum[r];
        for (int t = 0; t < 4; t++)
            for (int r = 0; r < 4; r++) Oacc[t][r] *= alpha[r];

        short* Pw = &Ps[w][0];
        for (int sub = 0; sub < 4; sub++)
            for (int r = 0; r < 4; r++)
                Pw[((l >> 4) * 4 + r) * 72 + sub * 16 + lrow] = f2bf(s[sub][r]);
        __syncthreads();   // conservative: guarantee P write->read ordering

        short8 ap0 = *(const short8*)&Pw[lrow * 72 + lk];
        short8 ap1 = *(const short8*)&Pw[lrow * 72 + 32 + lk];
        for (int ddt = 0; ddt < 4; ddt++) {
            short8 bv0 = *(const short8*)&Vt[(ddt * 16 + lrow) * 72 + lk];
            short8 bv1 = *(const short8*)&Vt[(ddt * 16 + lrow) * 72 + 32 + lk];
            Oacc[ddt] = __builtin_amdgcn_mfma_f32_16x16x32_bf16(ap0, bv0, Oacc[ddt], 0, 0, 0);
            Oacc[ddt] = __builtin_amdgcn_mfma_f32_16x16x32_bf16(ap1, bv1, Oacc[ddt], 0, 0, 0);
        }
    }

    float linv[4];
    for (int r = 0; r < 4; r++) linv[r] = 1.f / l_i[r];
    for (int ddt = 0; ddt < 4; ddt++)
        for (int r = 0; r < 4; r++) {
            int n = n0 + w * 16 + (l >> 4) * 4 + r;
            int dd = ddt * 16 + lrow;
            float v = Oacc[ddt][r] * linv[r];
            if (br == 0)
                out[((size_t)b * NTOK + n) * 512 + h * 64 + dd] = v;
            else
                out[(size_t)BNC + ((size_t)(h * 2 + b) * NTOK + n) * 64 + dd] = v;
        }
}

extern "C" void kernel_launch(void* const* d_in, const int* in_sizes, int n_in,
                              void* d_out, int out_size, void* d_ws, size_t ws_size,
                              hipStream_t stream) {
    const float* x     = (const float*)d_in[0];
    const float* y     = (const float*)d_in[1];
    const float* k_w   = (const float*)d_in[2];
    const float* k_b   = (const float*)d_in[3];
    const float* qv_w  = (const float*)d_in[4];
    const float* qv_b  = (const float*)d_in[5];
    const float* lnx_g = (const float*)d_in[6];
    const float* lnx_b = (const float*)d_in[7];
    const float* lny_g = (const float*)d_in[8];
    const float* lny_b = (const float*)d_in[9];
    float* out = (float*)d_out;

    char* ws = (char*)d_ws;
    float* mu   = (float*)ws;                 // 9216 f32
    float* rs   = mu + 9216;                  // 9216 f32
    float* bias = rs + 9216;                  // 1536 f32  (ends at 79872 B)
    short* T    = (short*)(ws + 79872);       // 4,718,592 bf16
    short* Wt   = T + 4718592;                // 786,432 bf16
    short* QVK  = Wt + 786432;                // 14,155,776 bf16
    short* VT   = QVK + 14155776;             // 4,718,592 bf16  (total ~48.8 MB)

    k_stats <<<36, 256, 0, stream>>>(x, y, mu, rs);
    k_wtrans<<<dim3(24, 8), 256, 0, stream>>>(qv_w, k_w, qv_b, k_b, Wt, bias);
    k_normT <<<dim3(36, 8, 4), 256, 0, stream>>>(x, y, mu, rs,
                                                 lnx_g, lnx_b, lny_g, lny_b, T);
    k_gemm  <<<dim3(36, 24, 4), 256, 0, stream>>>(T, Wt, bias, QVK);
    k_vtrans<<<dim3(36, 8, 4), 256, 0, stream>>>(QVK, VT);
    k_attn  <<<dim3(36, 32), 256, 0, stream>>>(QVK, VT, out);
}

// Round 2
// 277.378 us; speedup vs baseline: 1.1675x; 1.1675x over previous
//
#include <hip/hip_runtime.h>

#define DIM 512
#define NTOK 2304
#define HEADS 8
#define HD 64
#define SCALE 0.125f
#define LN_EPS 1e-5f
#define BNC 2359296   // B*N*C = 2*2304*512

typedef __attribute__((ext_vector_type(8))) short short8;
typedef __attribute__((ext_vector_type(4))) short sh4;
typedef __attribute__((ext_vector_type(4))) float f32x4;

__device__ __forceinline__ short f2bf(float f) {
    union { float f; unsigned u; } x; x.f = f;
    unsigned r = (x.u + 0x7fffu + ((x.u >> 16) & 1u)) >> 16;
    return (short)(r & 0xffffu);
}

// ---------------- LN stats: mu, rsigma per (stream, b, n) ----------------
__global__ void k_stats(const float* __restrict__ x, const float* __restrict__ y,
                        float* __restrict__ mu, float* __restrict__ rs) {
    int id = blockIdx.x * 256 + threadIdx.x;   // [s][b][n], 9216 total
    int n = id % NTOK;
    int sb = id / NTOK;                        // s*2+b
    int s = sb >> 1, b = sb & 1;
    const float* src = (s ? y : x) + (size_t)b * DIM * NTOK + n;
    float sum = 0.f, sq = 0.f;
    for (int c = 0; c < DIM; c++) {
        float v = src[(size_t)c * NTOK];
        sum += v; sq += v * v;
    }
    float m = sum * (1.0f / DIM);
    float var = sq * (1.0f / DIM) - m * m;
    mu[id] = m;
    rs[id] = rsqrtf(var + LN_EPS);
}

// ---------------- normalize + transpose -> T[s][b][n][c] bf16 ----------------
__global__ void k_normT(const float* __restrict__ x, const float* __restrict__ y,
                        const float* __restrict__ mu, const float* __restrict__ rs,
                        const float* __restrict__ gx, const float* __restrict__ bx,
                        const float* __restrict__ gy, const float* __restrict__ by,
                        short* __restrict__ T) {
    __shared__ __align__(16) float tile[64][65];
    int nt = blockIdx.x, ct = blockIdx.y, sb = blockIdx.z;
    int s = sb >> 1, b = sb & 1;
    int n0 = nt * 64, c0 = ct * 64;
    const float* src = (s ? y : x) + (size_t)b * DIM * NTOK;
    int tid = threadIdx.x;
    for (int slot = tid; slot < 1024; slot += 256) {
        int r = slot >> 4, q = slot & 15;
        const float* p = src + (size_t)(c0 + r) * NTOK + n0 + q * 4;
        float4 v = *(const float4*)p;
        tile[r][q*4+0] = v.x; tile[r][q*4+1] = v.y;
        tile[r][q*4+2] = v.z; tile[r][q*4+3] = v.w;
    }
    __syncthreads();
    const float* g  = s ? gy : gx;
    const float* be = s ? by : bx;
    int nr = tid >> 2, cg = tid & 3;
    int n = n0 + nr;
    float m = mu[sb * NTOK + n], r_ = rs[sb * NTOK + n];
    short8 o0, o1;
    for (int i = 0; i < 8; i++) {
        int c = c0 + cg * 16 + i;
        o0[i] = f2bf((tile[cg*16+i][nr] - m) * r_ * g[c] + be[c]);
    }
    for (int i = 0; i < 8; i++) {
        int c = c0 + cg * 16 + 8 + i;
        o1[i] = f2bf((tile[cg*16+8+i][nr] - m) * r_ * g[c] + be[c]);
    }
    short* dst = T + ((size_t)sb * NTOK + n) * DIM + c0 + cg * 16;
    *(short8*)dst = o0;
    *(short8*)(dst + 8) = o1;
}

// ------------- weight transpose: Wt[j][c] = W[c][j] bf16, + combined bias -------------
__global__ void k_wtrans(const float* __restrict__ qv_w, const float* __restrict__ k_w,
                         const float* __restrict__ qv_b, const float* __restrict__ k_b,
                         short* __restrict__ Wt, float* __restrict__ bias) {
    __shared__ __align__(16) float tile[64][65];
    int jt = blockIdx.x, ct = blockIdx.y;
    int j0 = jt * 64, c0 = ct * 64;
    int tid = threadIdx.x;
    if (ct == 0 && tid < 64) {
        int j = j0 + tid;
        bias[j] = (j < 1024) ? qv_b[j] : k_b[j - 1024];
    }
    for (int slot = tid; slot < 1024; slot += 256) {
        int r = slot >> 4, q = slot & 15;
        int c = c0 + r;
        float4 v;
        if (j0 < 1024) v = *(const float4*)(qv_w + (size_t)c * 1024 + j0 + q * 4);
        else           v = *(const float4*)(k_w  + (size_t)c * 512  + (j0 - 1024) + q * 4);
        tile[r][q*4+0] = v.x; tile[r][q*4+1] = v.y;
        tile[r][q*4+2] = v.z; tile[r][q*4+3] = v.w;
    }
    __syncthreads();
    int jr = tid >> 2, cg = tid & 3;
    short8 o0, o1;
    for (int i = 0; i < 8; i++) o0[i] = f2bf(tile[cg*16+i][jr]);
    for (int i = 0; i < 8; i++) o1[i] = f2bf(tile[cg*16+8+i][jr]);
    short* dst = Wt + (size_t)(j0 + jr) * DIM + c0 + cg * 16;
    *(short8*)dst = o0;
    *(short8*)(dst + 8) = o1;
}

// -------- GEMM: QVK[sb][n][j] = T[sb] @ W + bias, 128x128 tile, Q pre-scaled --------
__global__ void __launch_bounds__(256)
k_gemm(const short* __restrict__ T, const short* __restrict__ Wt,
       const float* __restrict__ bias, short* __restrict__ QVK) {
    __shared__ __align__(16) short As[128 * 72];
    __shared__ __align__(16) short Bs[128 * 72];
    int n0 = blockIdx.x * 128, j0 = blockIdx.y * 128, sb = blockIdx.z;
    int tid = threadIdx.x;
    int w = tid >> 6, l = tid & 63;
    int wr = w >> 1, wc = w & 1;
    int lrow = l & 15, quad = l >> 4, lk = quad * 8;
    const short* Ab = T + (size_t)sb * NTOK * DIM;
    f32x4 acc[4][4] = {};
    for (int kk = 0; kk < 8; kk++) {
        if (kk) __syncthreads();
        for (int slot = tid; slot < 1024; slot += 256) {
            int r = slot >> 3, seg = slot & 7;
            *(short8*)&As[r * 72 + seg * 8] =
                *(const short8*)(Ab + (size_t)(n0 + r) * DIM + kk * 64 + seg * 8);
            *(short8*)&Bs[r * 72 + seg * 8] =
                *(const short8*)(Wt + (size_t)(j0 + r) * DIM + kk * 64 + seg * 8);
        }
        __syncthreads();
        for (int c2 = 0; c2 < 2; c2++) {
            short8 af[4], bf[4];
            for (int i = 0; i < 4; i++)
                af[i] = *(const short8*)&As[(wr*64 + i*16 + lrow) * 72 + c2*32 + lk];
            for (int j = 0; j < 4; j++)
                bf[j] = *(const short8*)&Bs[(wc*64 + j*16 + lrow) * 72 + c2*32 + lk];
            for (int i = 0; i < 4; i++)
                for (int j = 0; j < 4; j++)
                    acc[i][j] = __builtin_amdgcn_mfma_f32_16x16x32_bf16(af[i], bf[j], acc[i][j], 0, 0, 0);
        }
    }
    for (int i = 0; i < 4; i++)
        for (int j = 0; j < 4; j++) {
            int jj = j0 + wc * 64 + j * 16 + lrow;
            float bv = bias[jj];
            float sc = (jj < 512) ? SCALE : 1.0f;   // pre-fold softmax scale into Q
            for (int reg = 0; reg < 4; reg++) {
                int n = n0 + wr * 64 + i * 16 + quad * 4 + reg;
                QVK[((size_t)sb * NTOK + n) * 1536 + jj] = f2bf((acc[i][j][reg] + bv) * sc);
            }
        }
}

// ---------------- V transpose: VT[sb][j][n] from QVK v-region ----------------
__global__ void k_vtrans(const short* __restrict__ QVK, short* __restrict__ VT) {
    __shared__ short tile[64][65];
    int n0 = blockIdx.x * 64, j0 = blockIdx.y * 64, sb = blockIdx.z;
    int tid = threadIdx.x;
    for (int slot = tid; slot < 512; slot += 256) {
        int r = slot >> 3, seg = slot & 7;
        short8 v = *(const short8*)(QVK + ((size_t)sb * NTOK + n0 + r) * 1536 + 512 + j0 + seg * 8);
        for (int i = 0; i < 8; i++) tile[r][seg * 8 + i] = v[i];
    }
    __syncthreads();
    int jr = tid >> 2, ng = tid & 3;
    short8 o0, o1;
    for (int i = 0; i < 8; i++) o0[i] = tile[ng*16+i][jr];
    for (int i = 0; i < 8; i++) o1[i] = tile[ng*16+8+i][jr];
    short* dst = VT + ((size_t)sb * 512 + j0 + jr) * NTOK + n0 + ng * 16;
    *(short8*)dst = o0;
    *(short8*)(dst + 8) = o1;
}

// ---------------- flash attention, S^T formulation ----------------
// QK mfma: A=K-frag(rows m), B=Q-frag(rows n) -> C = S^T: lane holds
// S[n=lane&15][m=quad*4+reg] per sub. Softmax state per-lane. P written to
// per-wave LDS (b64, conflict-free, no barrier), read back as x32 A-frag.
__global__ void __launch_bounds__(256)
k_attn(const short* __restrict__ QVK, const short* __restrict__ VT,
       float* __restrict__ out) {
    __shared__ __align__(16) short Ks[64 * 72];
    __shared__ __align__(16) short Vt[64 * 72];
    __shared__ __align__(16) short Qs[64 * 72];   // Q staging; re-used as P
    int qt = blockIdx.x;              // 0..35
    int yb = blockIdx.y;              // 0..31
    int br = yb >> 4;
    int b  = (yb >> 3) & 1;
    int h  = yb & 7;
    int tid = threadIdx.x;
    int w = tid >> 6, l = tid & 63;
    int lrow = l & 15, quad = l >> 4, lk = quad * 8;
    int n0 = qt * 64;
    const short* Qg = QVK + ((size_t)(br * 2 + b) * NTOK) * 1536 + h * 64;          // pre-scaled Q
    const short* Kg = QVK + ((size_t)((1 - br) * 2 + b) * NTOK) * 1536 + 1024 + h * 64;
    const short* Vg = VT + ((size_t)(br * 2 + b) * 512 + h * 64) * NTOK;

    for (int slot = tid; slot < 512; slot += 256) {
        int r = slot >> 3, seg = slot & 7;
        *(short8*)&Qs[r * 72 + seg * 8] =
            *(const short8*)(Qg + (size_t)(n0 + r) * 1536 + seg * 8);
    }
    __syncthreads();
    short8 bq0 = *(const short8*)&Qs[(w * 16 + lrow) * 72 + lk];
    short8 bq1 = *(const short8*)&Qs[(w * 16 + lrow) * 72 + 32 + lk];
    short* Pw = &Qs[w * 16 * 72];     // per-wave private P buffer (rows this wave read)

    f32x4 Oacc[4] = {};
    float m_i = -__builtin_inff(), l_i = 0.f;

    for (int mt = 0; mt < 36; mt++) {
        int m0 = mt * 64;
        __syncthreads();
        for (int slot = tid; slot < 512; slot += 256) {
            int r = slot >> 3, seg = slot & 7;
            *(short8*)&Ks[r * 72 + seg * 8] =
                *(const short8*)(Kg + (size_t)(m0 + r) * 1536 + seg * 8);
            *(short8*)&Vt[r * 72 + seg * 8] =
                *(const short8*)(Vg + (size_t)r * NTOK + m0 + seg * 8);
        }
        __syncthreads();

        f32x4 s[4];
        for (int sub = 0; sub < 4; sub++) {
            short8 ak0 = *(const short8*)&Ks[(sub * 16 + lrow) * 72 + lk];
            short8 ak1 = *(const short8*)&Ks[(sub * 16 + lrow) * 72 + 32 + lk];
            f32x4 a = {};
            a = __builtin_amdgcn_mfma_f32_16x16x32_bf16(ak0, bq0, a, 0, 0, 0);
            a = __builtin_amdgcn_mfma_f32_16x16x32_bf16(ak1, bq1, a, 0, 0, 0);
            s[sub] = a;
        }

        // per-lane softmax state for row n = w*16 + (l&15), replicated across quads
        float mx = s[0][0];
        for (int sub = 0; sub < 4; sub++)
            for (int r = 0; r < 4; r++) mx = fmaxf(mx, s[sub][r]);
        mx = fmaxf(mx, __shfl_xor(mx, 16, 64));
        mx = fmaxf(mx, __shfl_xor(mx, 32, 64));
        float nm = fmaxf(m_i, mx);
        float alpha = __expf(m_i - nm);
        m_i = nm;
        float rsum = 0.f;
        for (int sub = 0; sub < 4; sub++)
            for (int r = 0; r < 4; r++) {
                float p = __expf(s[sub][r] - nm);
                s[sub][r] = p;
                rsum += p;
            }
        rsum += __shfl_xor(rsum, 16, 64);
        rsum += __shfl_xor(rsum, 32, 64);
        l_i = l_i * alpha + rsum;

        // P^T rows: lane writes 4 consecutive m at [n=lrow][m=sub*16+quad*4]
        for (int sub = 0; sub < 4; sub++) {
            sh4 pk;
            for (int r = 0; r < 4; r++) pk[r] = f2bf(s[sub][r]);
            *(sh4*)&Pw[lrow * 72 + sub * 16 + quad * 4] = pk;
        }

        // rescale Oacc (rows n = quad*4+reg need alpha from lane quad*4+reg)
        float ar[4];
        for (int r = 0; r < 4; r++) ar[r] = __shfl(alpha, (l & 48) + quad * 4 + r, 64);
        for (int t = 0; t < 4; t++)
            for (int r = 0; r < 4; r++) Oacc[t][r] *= ar[r];

        // PV: A = P (rows n), B = Vt (rows d); same-wave LDS dep, no barrier
        short8 ap0 = *(const short8*)&Pw[lrow * 72 + lk];
        short8 ap1 = *(const short8*)&Pw[lrow * 72 + 32 + lk];
        for (int ddt = 0; ddt < 4; ddt++) {
            short8 bv0 = *(const short8*)&Vt[(ddt * 16 + lrow) * 72 + lk];
            short8 bv1 = *(const short8*)&Vt[(ddt * 16 + lrow) * 72 + 32 + lk];
            Oacc[ddt] = __builtin_amdgcn_mfma_f32_16x16x32_bf16(ap0, bv0, Oacc[ddt], 0, 0, 0);
            Oacc[ddt] = __builtin_amdgcn_mfma_f32_16x16x32_bf16(ap1, bv1, Oacc[ddt], 0, 0, 0);
        }
    }

    float li[4];
    for (int r = 0; r < 4; r++) {
        float lv = __shfl(l_i, (l & 48) + quad * 4 + r, 64);
        li[r] = 1.f / lv;
    }
    for (int ddt = 0; ddt < 4; ddt++)
        for (int r = 0; r < 4; r++) {
            int n = n0 + w * 16 + quad * 4 + r;
            int dd = ddt * 16 + lrow;
            float v = Oacc[ddt][r] * li[r];
            if (br == 0)
                out[((size_t)b * NTOK + n) * 512 + h * 64 + dd] = v;
            else
                out[(size_t)BNC + ((size_t)(h * 2 + b) * NTOK + n) * 64 + dd] = v;
        }
}

extern "C" void kernel_launch(void* const* d_in, const int* in_sizes, int n_in,
                              void* d_out, int out_size, void* d_ws, size_t ws_size,
                              hipStream_t stream) {
    const float* x     = (const float*)d_in[0];
    const float* y     = (const float*)d_in[1];
    const float* k_w   = (const float*)d_in[2];
    const float* k_b   = (const float*)d_in[3];
    const float* qv_w  = (const float*)d_in[4];
    const float* qv_b  = (const float*)d_in[5];
    const float* lnx_g = (const float*)d_in[6];
    const float* lnx_b = (const float*)d_in[7];
    const float* lny_g = (const float*)d_in[8];
    const float* lny_b = (const float*)d_in[9];
    float* out = (float*)d_out;

    char* ws = (char*)d_ws;
    float* mu   = (float*)ws;                 // 9216 f32
    float* rs   = mu + 9216;                  // 9216 f32
    float* bias = rs + 9216;                  // 1536 f32  (ends at 79872 B)
    short* T    = (short*)(ws + 79872);       // 4,718,592 bf16
    short* Wt   = T + 4718592;                // 786,432 bf16
    short* QVK  = Wt + 786432;                // 14,155,776 bf16
    short* VT   = QVK + 14155776;             // 4,718,592 bf16

    k_stats <<<36, 256, 0, stream>>>(x, y, mu, rs);
    k_wtrans<<<dim3(24, 8), 256, 0, stream>>>(qv_w, k_w, qv_b, k_b, Wt, bias);
    k_normT <<<dim3(36, 8, 4), 256, 0, stream>>>(x, y, mu, rs,
                                                 lnx_g, lnx_b, lny_g, lny_b, T);
    k_gemm  <<<dim3(18, 12, 4), 256, 0, stream>>>(T, Wt, bias, QVK);
    k_vtrans<<<dim3(36, 8, 4), 256, 0, stream>>>(QVK, VT);
    k_attn  <<<dim3(36, 32), 256, 0, stream>>>(QVK, VT, out);
}